// Round 8
// baseline (149.582 us; speedup 1.0000x reference)
//
#include <hip/hip_runtime.h>
#include <stdint.h>

// ---------------------------------------------------------------------------
// UnifiedEnergyFunction: total/hopfield/consistency/regularization scalars.
//   hopfield = mean_b( -logsumexp_n( z[b,:] . M[n,:] ) )
//   consistency = mean_b ||z - z_next||^2
//   regularization = 0.01 * mean_b ||z||^2
// v8: barrier-free lse kernel. M is pre-packed into MFMA A-fragment order and
// streamed L2 -> registers (ping-pong 4-load buffers); z fragments resident in
// regs; NO LDS, NO __syncthreads, no phase-lock. v4's L2-thrash root cause
// (8MB live per 4MB XCD L2) fixed by v5's proven NSPLIT=16 mapping (2x2MB).
// z pre-scaled by log2(e); acc init -69; epilogue = native v_exp_f32 + add.
// ---------------------------------------------------------------------------

typedef __attribute__((ext_vector_type(8))) short short8;
typedef __attribute__((ext_vector_type(4))) float f32x4;

#define N_PAT  65536
#define D_DIM  256
#define B_ROWS 4096
#define NSPLIT 16                 // M ranges (2 per XCD, 2MB each) — proven
#define NRANGE (N_PAT / NSPLIT)   // 4096 rows per range
#define SPR    (NRANGE / 16)      // 256 16-row fragment groups per range
#define SPERW  (SPR / 2)          // 128 groups per wave (nh parity split)
#define BBLK   128                // b rows per block (2 bh x 64)
#define SHIFT2 69.0f              // fixed shift in log2 domain (~48 nats)
#define LOG2E  1.44269504f
#define LN2    0.69314718f

// workspace layout (bytes)
#define WS_M_OFF   ((size_t)0)
#define WS_M_BYTES ((size_t)N_PAT * D_DIM * 2)      // 32 MB packed bf16 M
#define WS_Z_OFF   (WS_M_OFF + WS_M_BYTES)
#define WS_Z_BYTES ((size_t)B_ROWS * D_DIM * 2)     // 2 MB bf16 z*log2e
#define WS_LSE_OFF (WS_Z_OFF + WS_Z_BYTES)
#define WS_LSE_BYTES ((size_t)B_ROWS * NSPLIT * 2 * 4) // float S per (b, 32 parts)
#define WS_CSS_OFF (WS_LSE_OFF + WS_LSE_BYTES)
#define WS_ZSS_OFF (WS_CSS_OFF + (size_t)512 * 4)

__device__ __forceinline__ short f2bf(float f) {
  uint32_t u = __float_as_uint(f);
  uint32_t r = (u + 0x7fffu + ((u >> 16) & 1u)) >> 16;
  return (short)(r & 0xffffu);
}

__device__ __forceinline__ float fexp2(float x) {
  return __builtin_amdgcn_exp2f(x);   // v_exp_f32 (hardware base-2 exp)
}

__device__ __forceinline__ float waveRedAdd(float v) {
  #pragma unroll
  for (int o = 32; o > 0; o >>= 1) v += __shfl_down(v, o, 64);
  return v;
}

// ---------------------------------------------------------------- kernel A1
// Convert M f32 -> bf16 AND repack into 16x16x32 A-fragment streaming order:
//   Mp[s][kc][lane][e] = M[s*16 + (lane&15)][kc*32 + (lane>>4)*8 + e]
// (s = 16-row fragment group 0..4095, kc = K-chunk 0..7, e = 0..7)
// Reads are full 128B sectors (4 lanes x 32B per row); writes 1KB contiguous.
__global__ void convert_m_kernel(const float* __restrict__ src, short* __restrict__ dst) {
  const int s = blockIdx.x * 4 + (threadIdx.x >> 6);  // 0..4095 (grid 1024)
  const int lane = threadIdx.x & 63;
  const int l15 = lane & 15, grp = lane >> 4;
  const float* sp = src + ((size_t)s * 16 + l15) * D_DIM + grp * 8;
  short* dp = dst + ((size_t)s * 8 * 64 + lane) * 8;
  #pragma unroll
  for (int kc = 0; kc < 8; ++kc) {
    const float4 x = *(const float4*)(sp + kc * 32);
    const float4 y = *(const float4*)(sp + kc * 32 + 4);
    short8 o;
    o[0] = f2bf(x.x); o[1] = f2bf(x.y); o[2] = f2bf(x.z); o[3] = f2bf(x.w);
    o[4] = f2bf(y.x); o[5] = f2bf(y.y); o[6] = f2bf(y.z); o[7] = f2bf(y.w);
    *(short8*)(dp + (size_t)kc * 64 * 8) = o;
  }
}

// ---------------------------------------------------------------- kernel A2
// z -> bf16 scaled by log2(e), plus partial sums of ||z-zn||^2 and ||z||^2
__global__ void prep_z_kernel(const float* __restrict__ z, const float* __restrict__ zn,
                              short* __restrict__ zbf, float* __restrict__ css,
                              float* __restrict__ zss) {
  int t = blockIdx.x * 256 + threadIdx.x;  // 512 blocks x 256 = exactly B*D/8
  const float* az = z + (size_t)t * 8;
  const float* an = zn + (size_t)t * 8;
  float4 z0 = *(const float4*)(az), z1 = *(const float4*)(az + 4);
  float4 n0 = *(const float4*)(an), n1 = *(const float4*)(an + 4);
  float zv[8] = {z0.x, z0.y, z0.z, z0.w, z1.x, z1.y, z1.z, z1.w};
  float nv[8] = {n0.x, n0.y, n0.z, n0.w, n1.x, n1.y, n1.z, n1.w};
  short8 o;
  float cs = 0.f, zs = 0.f;
  #pragma unroll
  for (int j = 0; j < 8; ++j) {
    o[j] = f2bf(zv[j] * LOG2E);   // GEMM output lands in log2 domain
    float d = zv[j] - nv[j];
    cs += d * d;
    zs += zv[j] * zv[j];
  }
  *(short8*)(zbf + (size_t)t * 8) = o;

  __shared__ float rc[4], rz[4];
  cs = waveRedAdd(cs);
  zs = waveRedAdd(zs);
  int w = threadIdx.x >> 6, lane = threadIdx.x & 63;
  if (lane == 0) { rc[w] = cs; rz[w] = zs; }
  __syncthreads();
  if (threadIdx.x == 0) {
    css[blockIdx.x] = rc[0] + rc[1] + rc[2] + rc[3];
    zss[blockIdx.x] = rz[0] + rz[1] + rz[2] + rz[3];
  }
}

// ---------------------------------------------------------------- kernel B
// Barrier-free flash-LSE. 512 blocks x 4 waves; wave = (bh, nh):
//   bh: which 64 b-cols (zf resident, 128 regs)
//   nh: parity of 16-row fragment groups within this block's 4096-n range.
// Per group: {issue 4 A-frag loads (ping-pong) | 32 MFMA | 16x exp2}.
// A-frags stream from the packed Mp layout; each XCD's 2 live ranges = 4MB
// = its L2 capacity, so M is fetched from HBM ~once (v5-proven regime).
__global__ __launch_bounds__(256, 2) void lse_kernel(const short* __restrict__ Mp,
                                                     const short* __restrict__ zbf,
                                                     float* __restrict__ lsep) {
  const int bid = blockIdx.x;             // 512 blocks
  const int xcd = bid & 7;
  const int g = bid >> 3;                 // 0..63
  const int bblk = g & 31;
  const int half = g >> 5;
  const int nsplit = xcd * 2 + half;      // 2 ranges live per XCD

  const int tid = threadIdx.x;
  const int w = tid >> 6;
  const int lane = tid & 63;
  const int l15 = lane & 15;
  const int grp = lane >> 4;
  const int bh = w & 1;                   // b-half (64 cols)
  const int nh = w >> 1;                  // group parity

  // hoist z fragments: 4 b-subtiles x 8 k-chunks = 128 regs (one-time, L2/L3)
  short8 zf[4][8];
  const int brow0 = bblk * BBLK + bh * 64;
  #pragma unroll
  for (int bt = 0; bt < 4; ++bt) {
    #pragma unroll
    for (int kc = 0; kc < 8; ++kc) {
      int row = brow0 + bt * 16 + l15;
      zf[bt][kc] = *(const short8*)(zbf + (size_t)row * D_DIM + kc * 32 + grp * 8);
    }
  }

  // fragment stream base: s = nsplit*256 + nh + 2*j, j = 0..127
  // byte offset of (s, kc, lane) = ((s*8 + kc)*64 + lane)*16 = s*8192 + kc*1024 + lane*16
  const char* pj = (const char*)Mp + (size_t)(nsplit * SPR + nh) * 8192 + lane * 16;

  float ssum[4] = {0.f, 0.f, 0.f, 0.f};
  f32x4 acc[4];
  short8 afA[4], afB[4];

  // prologue: first half-group in flight
  #pragma unroll
  for (int kc = 0; kc < 4; ++kc) afA[kc] = *(const short8*)(pj + kc * 1024);

  for (int j = 0; j < SPERW; ++j) {
    const char* pn = pj + 16384;          // next group (s += 2)
    const char* ph = pj + 4096;           // second half of this group
    #pragma unroll
    for (int kc = 0; kc < 4; ++kc) afB[kc] = *(const short8*)(ph + kc * 1024);

    #pragma unroll
    for (int bt = 0; bt < 4; ++bt)
      #pragma unroll
      for (int q = 0; q < 4; ++q) acc[bt][q] = -SHIFT2;

    __builtin_amdgcn_s_setprio(1);
    #pragma unroll
    for (int kc = 0; kc < 4; ++kc)
      #pragma unroll
      for (int bt = 0; bt < 4; ++bt)
        acc[bt] = __builtin_amdgcn_mfma_f32_16x16x32_bf16(afA[kc], zf[bt][kc],
                                                          acc[bt], 0, 0, 0);
    __builtin_amdgcn_s_setprio(0);

    if (j + 1 < SPERW) {                  // prefetch next group's first half
      #pragma unroll
      for (int kc = 0; kc < 4; ++kc) afA[kc] = *(const short8*)(pn + kc * 1024);
    }

    __builtin_amdgcn_s_setprio(1);
    #pragma unroll
    for (int kc = 0; kc < 4; ++kc)
      #pragma unroll
      for (int bt = 0; bt < 4; ++bt)
        acc[bt] = __builtin_amdgcn_mfma_f32_16x16x32_bf16(afB[kc], zf[bt][kc + 4],
                                                          acc[bt], 0, 0, 0);
    __builtin_amdgcn_s_setprio(0);

    // epilogue: acc = log2-logit - SHIFT2; native exp2 + accumulate
    #pragma unroll
    for (int bt = 0; bt < 4; ++bt)
      ssum[bt] += (fexp2(acc[bt][0]) + fexp2(acc[bt][1])) +
                  (fexp2(acc[bt][2]) + fexp2(acc[bt][3]));

    pj = pn;
  }

  // 4 lane-groups hold different n-rows of each fragment for the same b-col
  #pragma unroll
  for (int bt = 0; bt < 4; ++bt) {
    ssum[bt] += __shfl_xor(ssum[bt], 16, 64);
    ssum[bt] += __shfl_xor(ssum[bt], 32, 64);
  }
  if (grp == 0) {
    #pragma unroll
    for (int bt = 0; bt < 4; ++bt) {
      int b = brow0 + bt * 16 + l15;
      lsep[(size_t)b * (NSPLIT * 2) + nsplit * 2 + nh] = ssum[bt];
    }
  }
}

// ---------------------------------------------------------------- kernel C
__global__ void finalize_kernel(const float* __restrict__ lsep, const float* __restrict__ css,
                                const float* __restrict__ zss, float* __restrict__ out) {
  __shared__ float r1[16], r2[16], r3[16];
  int tid = threadIdx.x;  // 1024
  float sum_lse = 0.f;
  for (int r = tid; r < B_ROWS; r += 1024) {
    float S = 0.f;
    #pragma unroll
    for (int i = 0; i < NSPLIT * 2; ++i) S += lsep[(size_t)r * (NSPLIT * 2) + i];
    sum_lse += SHIFT2 * LN2 + logf(S);   // back to nats
  }
  float cs = 0.f, zs = 0.f;
  if (tid < 512) { cs = css[tid]; zs = zss[tid]; }

  sum_lse = waveRedAdd(sum_lse);
  cs = waveRedAdd(cs);
  zs = waveRedAdd(zs);
  int w = tid >> 6, lane = tid & 63;
  if (lane == 0) { r1[w] = sum_lse; r2[w] = cs; r3[w] = zs; }
  __syncthreads();
  if (tid == 0) {
    float sl = 0.f, sc = 0.f, sz = 0.f;
    #pragma unroll
    for (int i = 0; i < 16; ++i) { sl += r1[i]; sc += r2[i]; sz += r3[i]; }
    float hop = -sl / (float)B_ROWS;
    float cons = sc / (float)B_ROWS;
    float reg = 0.01f * sz / (float)B_ROWS;
    out[0] = hop + cons + reg;
    out[1] = hop;
    out[2] = cons;
    out[3] = reg;
  }
}

// ---------------------------------------------------------------------------
extern "C" void kernel_launch(void* const* d_in, const int* in_sizes, int n_in,
                              void* d_out, int out_size, void* d_ws, size_t ws_size,
                              hipStream_t stream) {
  (void)in_sizes; (void)n_in; (void)out_size; (void)ws_size;
  const float* z  = (const float*)d_in[0];
  const float* zn = (const float*)d_in[1];
  const float* M  = (const float*)d_in[2];
  char* ws = (char*)d_ws;
  short* Mp  = (short*)(ws + WS_M_OFF);
  short* zbf = (short*)(ws + WS_Z_OFF);
  float* lsep = (float*)(ws + WS_LSE_OFF);
  float* css = (float*)(ws + WS_CSS_OFF);
  float* zss = (float*)(ws + WS_ZSS_OFF);

  convert_m_kernel<<<1024, 256, 0, stream>>>(M, Mp);
  prep_z_kernel<<<512, 256, 0, stream>>>(z, zn, zbf, css, zss);
  lse_kernel<<<512, 256, 0, stream>>>(Mp, zbf, lsep);
  finalize_kernel<<<1, 1024, 0, stream>>>(lsep, css, zss, (float*)d_out);
}

// Round 9
// 146.033 us; speedup vs baseline: 1.0243x; 1.0243x over previous
//
#include <hip/hip_runtime.h>
#include <stdint.h>

// ---------------------------------------------------------------------------
// UnifiedEnergyFunction: total/hopfield/consistency/regularization scalars.
//   hopfield = mean_b( -logsumexp_n( z[b,:] . M[n,:] ) )
//   consistency = mean_b ||z - z_next||^2
//   regularization = 0.01 * mean_b ||z||^2
// v9 = v8 (barrier-free, 118us: M pre-packed + streamed L2->reg, zf in AGPRs,
// FETCH 24.6MB) + group-level double accumulator: group j's 32 MFMAs are
// issued, then group j-1's exp2 drain runs on the trans pipe while the matrix
// pipe executes. +16 regs only (acc set is 16), inside the 240<=256 budget.
// ---------------------------------------------------------------------------

typedef __attribute__((ext_vector_type(8))) short short8;
typedef __attribute__((ext_vector_type(4))) float f32x4;

#define N_PAT  65536
#define D_DIM  256
#define B_ROWS 4096
#define NSPLIT 16                 // M ranges (2 per XCD, 2MB each) — proven
#define NRANGE (N_PAT / NSPLIT)   // 4096 rows per range
#define SPR    (NRANGE / 16)      // 256 16-row fragment groups per range
#define SPERW  (SPR / 2)          // 128 groups per wave (nh parity split)
#define BBLK   128                // b rows per block (2 bh x 64)
#define SHIFT2 69.0f              // fixed shift in log2 domain (~48 nats)
#define LOG2E  1.44269504f
#define LN2    0.69314718f

// workspace layout (bytes)
#define WS_M_OFF   ((size_t)0)
#define WS_M_BYTES ((size_t)N_PAT * D_DIM * 2)      // 32 MB packed bf16 M
#define WS_Z_OFF   (WS_M_OFF + WS_M_BYTES)
#define WS_Z_BYTES ((size_t)B_ROWS * D_DIM * 2)     // 2 MB bf16 z*log2e
#define WS_LSE_OFF (WS_Z_OFF + WS_Z_BYTES)
#define WS_LSE_BYTES ((size_t)B_ROWS * NSPLIT * 2 * 4) // float S per (b, 32 parts)
#define WS_CSS_OFF (WS_LSE_OFF + WS_LSE_BYTES)
#define WS_ZSS_OFF (WS_CSS_OFF + (size_t)512 * 4)

__device__ __forceinline__ short f2bf(float f) {
  uint32_t u = __float_as_uint(f);
  uint32_t r = (u + 0x7fffu + ((u >> 16) & 1u)) >> 16;
  return (short)(r & 0xffffu);
}

__device__ __forceinline__ float fexp2(float x) {
  return __builtin_amdgcn_exp2f(x);   // v_exp_f32 (hardware base-2 exp)
}

__device__ __forceinline__ float waveRedAdd(float v) {
  #pragma unroll
  for (int o = 32; o > 0; o >>= 1) v += __shfl_down(v, o, 64);
  return v;
}

// ---------------------------------------------------------------- kernel A1
// Convert M f32 -> bf16 AND repack into 16x16x32 A-fragment streaming order:
//   Mp[s][kc][lane][e] = M[s*16 + (lane&15)][kc*32 + (lane>>4)*8 + e]
__global__ void convert_m_kernel(const float* __restrict__ src, short* __restrict__ dst) {
  const int s = blockIdx.x * 4 + (threadIdx.x >> 6);  // 0..4095 (grid 1024)
  const int lane = threadIdx.x & 63;
  const int l15 = lane & 15, grp = lane >> 4;
  const float* sp = src + ((size_t)s * 16 + l15) * D_DIM + grp * 8;
  short* dp = dst + ((size_t)s * 8 * 64 + lane) * 8;
  #pragma unroll
  for (int kc = 0; kc < 8; ++kc) {
    const float4 x = *(const float4*)(sp + kc * 32);
    const float4 y = *(const float4*)(sp + kc * 32 + 4);
    short8 o;
    o[0] = f2bf(x.x); o[1] = f2bf(x.y); o[2] = f2bf(x.z); o[3] = f2bf(x.w);
    o[4] = f2bf(y.x); o[5] = f2bf(y.y); o[6] = f2bf(y.z); o[7] = f2bf(y.w);
    *(short8*)(dp + (size_t)kc * 64 * 8) = o;
  }
}

// ---------------------------------------------------------------- kernel A2
// z -> bf16 scaled by log2(e), plus partial sums of ||z-zn||^2 and ||z||^2
__global__ void prep_z_kernel(const float* __restrict__ z, const float* __restrict__ zn,
                              short* __restrict__ zbf, float* __restrict__ css,
                              float* __restrict__ zss) {
  int t = blockIdx.x * 256 + threadIdx.x;  // 512 blocks x 256 = exactly B*D/8
  const float* az = z + (size_t)t * 8;
  const float* an = zn + (size_t)t * 8;
  float4 z0 = *(const float4*)(az), z1 = *(const float4*)(az + 4);
  float4 n0 = *(const float4*)(an), n1 = *(const float4*)(an + 4);
  float zv[8] = {z0.x, z0.y, z0.z, z0.w, z1.x, z1.y, z1.z, z1.w};
  float nv[8] = {n0.x, n0.y, n0.z, n0.w, n1.x, n1.y, n1.z, n1.w};
  short8 o;
  float cs = 0.f, zs = 0.f;
  #pragma unroll
  for (int j = 0; j < 8; ++j) {
    o[j] = f2bf(zv[j] * LOG2E);   // GEMM output lands in log2 domain
    float d = zv[j] - nv[j];
    cs += d * d;
    zs += zv[j] * zv[j];
  }
  *(short8*)(zbf + (size_t)t * 8) = o;

  __shared__ float rc[4], rz[4];
  cs = waveRedAdd(cs);
  zs = waveRedAdd(zs);
  int w = threadIdx.x >> 6, lane = threadIdx.x & 63;
  if (lane == 0) { rc[w] = cs; rz[w] = zs; }
  __syncthreads();
  if (threadIdx.x == 0) {
    css[blockIdx.x] = rc[0] + rc[1] + rc[2] + rc[3];
    zss[blockIdx.x] = rz[0] + rz[1] + rz[2] + rz[3];
  }
}

// ---------------------------------------------------------------- kernel B
// Barrier-free flash-LSE with a 2-deep accumulator pipeline.
// 512 blocks x 4 waves; wave = (bh, nh). Per group j:
//   {load 2nd-half A-frags | init+32 MFMA into CUR | prefetch j+1 1st half |
//    drain PREV's 16 exp2 (trans pipe, overlaps in-flight MFMAs)}.
__global__ __launch_bounds__(256, 2) void lse_kernel(const short* __restrict__ Mp,
                                                     const short* __restrict__ zbf,
                                                     float* __restrict__ lsep) {
  const int bid = blockIdx.x;             // 512 blocks
  const int xcd = bid & 7;
  const int g = bid >> 3;                 // 0..63
  const int bblk = g & 31;
  const int half = g >> 5;
  const int nsplit = xcd * 2 + half;      // 2 ranges live per XCD

  const int tid = threadIdx.x;
  const int w = tid >> 6;
  const int lane = tid & 63;
  const int l15 = lane & 15;
  const int grp = lane >> 4;
  const int bh = w & 1;                   // b-half (64 cols)
  const int nh = w >> 1;                  // group parity

  // hoist z fragments: 4 b-subtiles x 8 k-chunks = 128 regs (AGPR-resident)
  short8 zf[4][8];
  const int brow0 = bblk * BBLK + bh * 64;
  #pragma unroll
  for (int bt = 0; bt < 4; ++bt) {
    #pragma unroll
    for (int kc = 0; kc < 8; ++kc) {
      int row = brow0 + bt * 16 + l15;
      zf[bt][kc] = *(const short8*)(zbf + (size_t)row * D_DIM + kc * 32 + grp * 8);
    }
  }

  // fragment stream: s = nsplit*256 + nh + 2*j; byte(s,kc,lane) = s*8192+kc*1024+lane*16
  const char* pj = (const char*)Mp + (size_t)(nsplit * SPR + nh) * 8192 + lane * 16;

  float ssum[4] = {0.f, 0.f, 0.f, 0.f};
  f32x4 accA[4], accB[4];
  short8 afA[4], afB[4];

  // accB pre-drained state: -inf so the first (dummy) drain adds exp2(-inf)=0
  #pragma unroll
  for (int bt = 0; bt < 4; ++bt)
    #pragma unroll
    for (int q = 0; q < 4; ++q) accB[bt][q] = -INFINITY;

  // prologue: first half-group in flight
  #pragma unroll
  for (int kc = 0; kc < 4; ++kc) afA[kc] = *(const short8*)(pj + kc * 1024);

  // group body: compute CUR (32 MFMA), then drain PREV (16 exp2, independent)
  auto body = [&](f32x4 (&CUR)[4], f32x4 (&PREV)[4]) {
    const char* ph = pj + 4096;           // second half of this group
    const char* pn = pj + 16384;          // next group (s += 2)
    #pragma unroll
    for (int kc = 0; kc < 4; ++kc) afB[kc] = *(const short8*)(ph + kc * 1024);

    #pragma unroll
    for (int bt = 0; bt < 4; ++bt)
      #pragma unroll
      for (int q = 0; q < 4; ++q) CUR[bt][q] = -SHIFT2;

    __builtin_amdgcn_s_setprio(1);
    #pragma unroll
    for (int kc = 0; kc < 4; ++kc)
      #pragma unroll
      for (int bt = 0; bt < 4; ++bt)
        CUR[bt] = __builtin_amdgcn_mfma_f32_16x16x32_bf16(afA[kc], zf[bt][kc],
                                                          CUR[bt], 0, 0, 0);
    __builtin_amdgcn_s_setprio(0);

    // prefetch next group's first half (unconditional; tail lands in d_ws)
    #pragma unroll
    for (int kc = 0; kc < 4; ++kc) afA[kc] = *(const short8*)(pn + kc * 1024);

    __builtin_amdgcn_s_setprio(1);
    #pragma unroll
    for (int kc = 0; kc < 4; ++kc)
      #pragma unroll
      for (int bt = 0; bt < 4; ++bt)
        CUR[bt] = __builtin_amdgcn_mfma_f32_16x16x32_bf16(afB[kc], zf[bt][kc + 4],
                                                          CUR[bt], 0, 0, 0);
    __builtin_amdgcn_s_setprio(0);

    // drain PREVIOUS group's accumulator: trans-pipe work, independent of the
    // in-flight MFMAs above -> overlaps on separate pipes
    #pragma unroll
    for (int bt = 0; bt < 4; ++bt)
      ssum[bt] += (fexp2(PREV[bt][0]) + fexp2(PREV[bt][1])) +
                  (fexp2(PREV[bt][2]) + fexp2(PREV[bt][3]));

    pj = pn;
  };

  #pragma unroll 1
  for (int jp = 0; jp < SPERW / 2; ++jp) {
    body(accA, accB);   // even group: compute A, drain B
    body(accB, accA);   // odd group:  compute B, drain A
  }

  // final drain (accB computed last)
  #pragma unroll
  for (int bt = 0; bt < 4; ++bt)
    ssum[bt] += (fexp2(accB[bt][0]) + fexp2(accB[bt][1])) +
                (fexp2(accB[bt][2]) + fexp2(accB[bt][3]));

  // 4 lane-groups hold different n-rows of each fragment for the same b-col
  #pragma unroll
  for (int bt = 0; bt < 4; ++bt) {
    ssum[bt] += __shfl_xor(ssum[bt], 16, 64);
    ssum[bt] += __shfl_xor(ssum[bt], 32, 64);
  }
  if (grp == 0) {
    #pragma unroll
    for (int bt = 0; bt < 4; ++bt) {
      int b = brow0 + bt * 16 + l15;
      lsep[(size_t)b * (NSPLIT * 2) + nsplit * 2 + nh] = ssum[bt];
    }
  }
}

// ---------------------------------------------------------------- kernel C
__global__ void finalize_kernel(const float* __restrict__ lsep, const float* __restrict__ css,
                                const float* __restrict__ zss, float* __restrict__ out) {
  __shared__ float r1[16], r2[16], r3[16];
  int tid = threadIdx.x;  // 1024
  float sum_lse = 0.f;
  for (int r = tid; r < B_ROWS; r += 1024) {
    float S = 0.f;
    #pragma unroll
    for (int i = 0; i < NSPLIT * 2; ++i) S += lsep[(size_t)r * (NSPLIT * 2) + i];
    sum_lse += SHIFT2 * LN2 + logf(S);   // back to nats
  }
  float cs = 0.f, zs = 0.f;
  if (tid < 512) { cs = css[tid]; zs = zss[tid]; }

  sum_lse = waveRedAdd(sum_lse);
  cs = waveRedAdd(cs);
  zs = waveRedAdd(zs);
  int w = tid >> 6, lane = tid & 63;
  if (lane == 0) { r1[w] = sum_lse; r2[w] = cs; r3[w] = zs; }
  __syncthreads();
  if (tid == 0) {
    float sl = 0.f, sc = 0.f, sz = 0.f;
    #pragma unroll
    for (int i = 0; i < 16; ++i) { sl += r1[i]; sc += r2[i]; sz += r3[i]; }
    float hop = -sl / (float)B_ROWS;
    float cons = sc / (float)B_ROWS;
    float reg = 0.01f * sz / (float)B_ROWS;
    out[0] = hop + cons + reg;
    out[1] = hop;
    out[2] = cons;
    out[3] = reg;
  }
}

// ---------------------------------------------------------------------------
extern "C" void kernel_launch(void* const* d_in, const int* in_sizes, int n_in,
                              void* d_out, int out_size, void* d_ws, size_t ws_size,
                              hipStream_t stream) {
  (void)in_sizes; (void)n_in; (void)out_size; (void)ws_size;
  const float* z  = (const float*)d_in[0];
  const float* zn = (const float*)d_in[1];
  const float* M  = (const float*)d_in[2];
  char* ws = (char*)d_ws;
  short* Mp  = (short*)(ws + WS_M_OFF);
  short* zbf = (short*)(ws + WS_Z_OFF);
  float* lsep = (float*)(ws + WS_LSE_OFF);
  float* css = (float*)(ws + WS_CSS_OFF);
  float* zss = (float*)(ws + WS_ZSS_OFF);

  convert_m_kernel<<<1024, 256, 0, stream>>>(M, Mp);
  prep_z_kernel<<<512, 256, 0, stream>>>(z, zn, zbf, css, zss);
  lse_kernel<<<512, 256, 0, stream>>>(Mp, zbf, lsep);
  finalize_kernel<<<1, 1024, 0, stream>>>(lsep, css, zss, (float*)d_out);
}